// Round 5
// baseline (2729.518 us; speedup 1.0000x reference)
//
#include <hip/hip_runtime.h>
#include <hip/hip_bf16.h>

using bf16 = __hip_bfloat16;
typedef __attribute__((ext_vector_type(8))) short bf16x8;
typedef __attribute__((ext_vector_type(4))) float f32x4;

static constexpr int HD = 2048;   // hidden
static constexpr int BB = 512;    // batch
static constexpr int OD = 512;    // output dim
static constexpr int TT = 32;     // time steps

#define MFMA(a, b, c) __builtin_amdgcn_mfma_f32_16x16x32_bf16((a), (b), (c), 0, 0, 0)

__device__ __forceinline__ void gld16(const void* g, void* l) {
  __builtin_amdgcn_global_load_lds((const __attribute__((address_space(1))) void*)g,
                                   (__attribute__((address_space(3))) void*)l, 16, 0, 0);
}

// one-time fp32 -> bf16 conversion
__global__ __launch_bounds__(256) void cvt_kernel(const float* __restrict__ s,
                                                  bf16* __restrict__ d, int n4) {
  const int i = blockIdx.x * 256 + threadIdx.x;
  if (i < n4) {
    const float4 v = ((const float4*)s)[i];
    union { unsigned long long u; bf16 e[4]; } o;
    o.e[0] = __float2bfloat16(v.x); o.e[1] = __float2bfloat16(v.y);
    o.e[2] = __float2bfloat16(v.z); o.e[3] = __float2bfloat16(v.w);
    *(unsigned long long*)(d + 4l * i) = o.u;
  }
}

// Fused GRU cell. Staging-BW model (round-4 post-mortem): gld16+L2 service
// ceiling ~25 B/cyc/CU; staged bytes/MAC = 2(1/BN+1/BM). Round-4's 64m tile
// = 0.052 B/MAC (ceiling hit). This round: 128m x 96n tile, grid 256 =
// 1 block/CU (full-utilization tiling for 512x6144 output), 0.036 B/MAC.
// Schedule unchanged from round 4 (proven): 3-buffer depth-2 counted-vmcnt
// (waves may idle in the wait; DMA queue stays full since stage(s+2) is
// issued pre-wait), BK=64, XOR swizzle (conflicts=0, verified r1-r4).
// Block: 128m x 32n x 3 gates, 4 waves; wave = 64m x 16n x 3 gates
// (24 MFMA + 14 ds_read_b128 per step). LDS 3 x 28KB ([A 16KB | W 12KB]).
// Per step: A-waves (w<2) 8 gld16 each -> vmcnt(8); W-waves 6 -> vmcnt(6).
#define CELL_COMPUTE(NACC)                                                     \
  {                                                                            \
    const char* aB = rb + (wm * 64 + cl) * 128;                                \
    const char* wB = rb + 16384 + (wn * 16 + cl) * 128;                        \
    bf16x8 a00 = *(const bf16x8*)(aB + sc0);                                   \
    bf16x8 a01 = *(const bf16x8*)(aB + sc1);                                   \
    bf16x8 a10 = *(const bf16x8*)(aB + 2048 + sc0);                            \
    bf16x8 a11 = *(const bf16x8*)(aB + 2048 + sc1);                            \
    bf16x8 a20 = *(const bf16x8*)(aB + 4096 + sc0);                            \
    bf16x8 a21 = *(const bf16x8*)(aB + 4096 + sc1);                            \
    bf16x8 a30 = *(const bf16x8*)(aB + 6144 + sc0);                            \
    bf16x8 a31 = *(const bf16x8*)(aB + 6144 + sc1);                            \
    bf16x8 w00 = *(const bf16x8*)(wB + sc0);                                   \
    bf16x8 w01 = *(const bf16x8*)(wB + sc1);                                   \
    bf16x8 w10 = *(const bf16x8*)(wB + 4096 + sc0);                            \
    bf16x8 w11 = *(const bf16x8*)(wB + 4096 + sc1);                            \
    bf16x8 w20 = *(const bf16x8*)(wB + 8192 + sc0);                            \
    bf16x8 w21 = *(const bf16x8*)(wB + 8192 + sc1);                            \
    acc[0][0] = MFMA(a00, w00, acc[0][0]);                                     \
    acc[0][1] = MFMA(a10, w00, acc[0][1]);                                     \
    acc[0][2] = MFMA(a20, w00, acc[0][2]);                                     \
    acc[0][3] = MFMA(a30, w00, acc[0][3]);                                     \
    acc[1][0] = MFMA(a00, w10, acc[1][0]);                                     \
    acc[1][1] = MFMA(a10, w10, acc[1][1]);                                     \
    acc[1][2] = MFMA(a20, w10, acc[1][2]);                                     \
    acc[1][3] = MFMA(a30, w10, acc[1][3]);                                     \
    acc[NACC][0] = MFMA(a00, w20, acc[NACC][0]);                               \
    acc[NACC][1] = MFMA(a10, w20, acc[NACC][1]);                               \
    acc[NACC][2] = MFMA(a20, w20, acc[NACC][2]);                               \
    acc[NACC][3] = MFMA(a30, w20, acc[NACC][3]);                               \
    acc[0][0] = MFMA(a01, w01, acc[0][0]);                                     \
    acc[0][1] = MFMA(a11, w01, acc[0][1]);                                     \
    acc[0][2] = MFMA(a21, w01, acc[0][2]);                                     \
    acc[0][3] = MFMA(a31, w01, acc[0][3]);                                     \
    acc[1][0] = MFMA(a01, w11, acc[1][0]);                                     \
    acc[1][1] = MFMA(a11, w11, acc[1][1]);                                     \
    acc[1][2] = MFMA(a21, w11, acc[1][2]);                                     \
    acc[1][3] = MFMA(a31, w11, acc[1][3]);                                     \
    acc[NACC][0] = MFMA(a01, w21, acc[NACC][0]);                               \
    acc[NACC][1] = MFMA(a11, w21, acc[NACC][1]);                               \
    acc[NACC][2] = MFMA(a21, w21, acc[NACC][2]);                               \
    acc[NACC][3] = MFMA(a31, w21, acc[NACC][3]);                               \
  }

#define CELL_ROT(P) P = (P == smem + 2 * 28672) ? smem : P + 28672;

#define CELL_STEP(NACC, STAGE_CALL)                                            \
  {                                                                            \
    if (w < 2) asm volatile("s_waitcnt vmcnt(8)\n\ts_barrier" ::: "memory");   \
    else       asm volatile("s_waitcnt vmcnt(6)\n\ts_barrier" ::: "memory");   \
    STAGE_CALL;                                                                \
    CELL_COMPUTE(NACC);                                                        \
    CELL_ROT(rb); CELL_ROT(sb);                                                \
  }

#define CELL_STEP_LAST(NACC)                                                   \
  {                                                                            \
    asm volatile("s_waitcnt vmcnt(0)\n\ts_barrier" ::: "memory");              \
    CELL_COMPUTE(NACC);                                                        \
  }

__global__ __launch_bounds__(256) void gru_cell_kernel(
    const bf16* __restrict__ Ax, int Kx,        // [B, Kx] bf16 layer input
    const bf16* __restrict__ Ahb,               // [B, H] bf16 h shadow
    const float* __restrict__ hprevf,           // [B, H] fp32 h master
    const bf16* __restrict__ Wih,               // [3H, Kx] bf16
    const bf16* __restrict__ Whh,               // [3H, H] bf16
    const float* __restrict__ bih, const float* __restrict__ bhh,
    float* __restrict__ houtf, bf16* __restrict__ houtb) {
  __shared__ __align__(1024) char smem[3 * 28672];  // [A 16KB | W 12KB] x 3
  const int tid = threadIdx.x;
  const int lane = tid & 63;
  const int w = __builtin_amdgcn_readfirstlane(tid >> 6);
  const int wm = w >> 1, wn = w & 1;
  const int bid = blockIdx.x;
  const int rest = bid >> 3;
  const int m0 = (rest >> 3) * 128;               // 4 m-groups
  const int n0 = ((bid & 7) * 8 + (rest & 7)) * 32;  // same-n -> same XCD
  const int lr8 = lane >> 3;                       // stage: row within 8
  const int gsw = ((lane & 7) ^ lr8) << 3;         // stage: swizzled k-elem off
  const int cl = lane & 15, q = lane >> 4;
  const int sc0 = ((q ^ (cl & 7)) << 4);           // read: swizzled col, h=0
  const int sc1 = sc0 ^ 64;                        // h=1
  const int nsa = Kx >> 6, nsb = HD >> 6;

  // acc: 0=r, 1=z (both phases), 2=gx_n (A), 3=gh_n (B); [gate][m-frag]
  f32x4 acc[4][4];
#pragma unroll
  for (int a = 0; a < 4; ++a)
#pragma unroll
    for (int i = 0; i < 4; ++i) acc[a][i] = (f32x4){0.f, 0.f, 0.f, 0.f};

  // stage K-slice s (64 wide) of (Ap,Wp) into buffer at base. Each gld16:
  // 8 rows x 128B = 1KB. waves 0-1: A (8 issues); waves 2-3: W (6 issues).
  auto stage = [&](const bf16* Ap, const bf16* Wp, int K, int s, char* base) {
    const int k0 = (s << 6) + gsw;
    if (w < 2) {
#pragma unroll
      for (int it = 0; it < 8; ++it) {
        const int r0 = (w * 8 + it) * 8;
        gld16(Ap + (long)(m0 + r0 + lr8) * K + k0, base + r0 * 128);
      }
    } else {
#pragma unroll
      for (int it = 0; it < 6; ++it) {
        const int jj = (w - 2) * 6 + it;           // 0..11: gate jj>>2, nn (jj&3)*8
        gld16(Wp + ((long)(jj >> 2) * HD + n0 + (jj & 3) * 8 + lr8) * K + k0,
              base + 16384 + jj * 1024);
      }
    }
  };

  stage(Ax, Wih, Kx, 0, smem);
  stage(Ax, Wih, Kx, 1, smem + 28672);   // nsa >= 8 always, slice 1 is phase A
  char* rb = smem;
  char* sb = smem + 2 * 28672;

  for (int s = 0; s < nsa; ++s)                  // phase A: x @ Wih^T
    CELL_STEP(2, if (s + 2 < nsa) stage(Ax, Wih, Kx, s + 2, sb);
                 else stage(Ahb, Whh, HD, s + 2 - nsa, sb));
  for (int s = 0; s < nsb - 1; ++s)              // phase B: h @ Whh^T
    CELL_STEP(3, if (s + 2 < nsb) stage(Ahb, Whh, HD, s + 2, sb));
  CELL_STEP_LAST(3);

  // C/D layout: col=lane&15, row=(lane>>4)*4+reg (m89-verified)
  const int j = n0 + wn * 16 + cl;
  const float bihr = bih[j], bihz = bih[j + HD], bihn = bih[j + 2 * HD];
  const float bhhr = bhh[j], bhhz = bhh[j + HD], bhhn = bhh[j + 2 * HD];
#pragma unroll
  for (int mi = 0; mi < 4; ++mi)
#pragma unroll
    for (int r = 0; r < 4; ++r) {
      const int b = m0 + wm * 64 + mi * 16 + q * 4 + r;
      const float gr = acc[0][mi][r] + bihr + bhhr;
      const float gz = acc[1][mi][r] + bihz + bhhz;
      const float gnx = acc[2][mi][r] + bihn;
      const float gnh = acc[3][mi][r] + bhhn;
      const float rr = 1.f / (1.f + __expf(-gr));
      const float zz = 1.f / (1.f + __expf(-gz));
      const float nn = tanhf(gnx + rr * gnh);
      const float hp = hprevf[(long)b * HD + j];
      const float hn = (1.f - zz) * nn + zz * hp;
      houtf[(long)b * HD + j] = hn;
      houtb[(long)b * HD + j] = __float2bfloat16(hn);
    }
}

// C = A @ W^T + bias, tile 64m x 64n, 4 waves (wave = 64m x 16n), BK=64,
// 3-buffer depth-2 counted-vmcnt (4 issues/wave/slice -> vmcnt(4)) + swizzle.
// mode 0: embedding — relu, scatter rows (b*2+l) into h0/h1 (fp32+bf16)
// mode 1: projection — preds[b,t,:] fp32 + xbuf bf16
#define G64_COMPUTE                                                            \
  {                                                                            \
    const char* aB = rb + cl * 128;                                            \
    const char* wB = rb + 8192 + (w * 16 + cl) * 128;                          \
    bf16x8 a00 = *(const bf16x8*)(aB + sc0);                                   \
    bf16x8 a01 = *(const bf16x8*)(aB + sc1);                                   \
    bf16x8 a10 = *(const bf16x8*)(aB + 2048 + sc0);                            \
    bf16x8 a11 = *(const bf16x8*)(aB + 2048 + sc1);                            \
    bf16x8 a20 = *(const bf16x8*)(aB + 4096 + sc0);                            \
    bf16x8 a21 = *(const bf16x8*)(aB + 4096 + sc1);                            \
    bf16x8 a30 = *(const bf16x8*)(aB + 6144 + sc0);                            \
    bf16x8 a31 = *(const bf16x8*)(aB + 6144 + sc1);                            \
    bf16x8 w0 = *(const bf16x8*)(wB + sc0);                                    \
    bf16x8 w1 = *(const bf16x8*)(wB + sc1);                                    \
    acc[0] = MFMA(a00, w0, acc[0]);                                            \
    acc[1] = MFMA(a10, w0, acc[1]);                                            \
    acc[2] = MFMA(a20, w0, acc[2]);                                            \
    acc[3] = MFMA(a30, w0, acc[3]);                                            \
    acc[0] = MFMA(a01, w1, acc[0]);                                            \
    acc[1] = MFMA(a11, w1, acc[1]);                                            \
    acc[2] = MFMA(a21, w1, acc[2]);                                            \
    acc[3] = MFMA(a31, w1, acc[3]);                                            \
  }

__global__ __launch_bounds__(256) void gemm64_kernel(
    const bf16* __restrict__ A, const bf16* __restrict__ W,
    const float* __restrict__ bias, int K, int mode, int t, int nbits,
    float* __restrict__ o0f, bf16* __restrict__ o0b,
    float* __restrict__ o1f, bf16* __restrict__ o1b,
    float* __restrict__ preds, bf16* __restrict__ xbuf) {
  __shared__ __align__(1024) char smem[3 * 16384];  // [A 8KB | W 8KB] x 3
  const int tid = threadIdx.x;
  const int lane = tid & 63;
  const int w = __builtin_amdgcn_readfirstlane(tid >> 6);
  const int bid = blockIdx.x;
  const int rest = bid >> 3;
  const int m0 = (rest >> nbits) * 64;
  const int n0 = (((bid & 7) << nbits) + (rest & ((1 << nbits) - 1))) * 64;
  const int lr8 = lane >> 3;
  const int gsw = ((lane & 7) ^ lr8) << 3;
  const int cl = lane & 15, q = lane >> 4;
  const int sc0 = ((q ^ (cl & 7)) << 4);
  const int sc1 = sc0 ^ 64;
  const int ns = K >> 6;

  f32x4 acc[4];
#pragma unroll
  for (int i = 0; i < 4; ++i) acc[i] = (f32x4){0.f, 0.f, 0.f, 0.f};

  auto stage = [&](int s, char* base) {
    const int k0 = (s << 6) + gsw;
    if (w < 2) {
#pragma unroll
      for (int it = 0; it < 4; ++it) {
        const int r0 = (w * 4 + it) * 8;
        gld16(A + (long)(m0 + r0 + lr8) * K + k0, base + r0 * 128);
      }
    } else {
#pragma unroll
      for (int it = 0; it < 4; ++it) {
        const int jj = (w - 2) * 4 + it;           // 0..7
        gld16(W + (long)(n0 + jj * 8 + lr8) * K + k0, base + 8192 + jj * 1024);
      }
    }
  };

  stage(0, smem);
  stage(1, smem + 16384);
  char* rb = smem;
  char* sb = smem + 2 * 16384;

  for (int s = 0; s < ns - 1; ++s) {
    asm volatile("s_waitcnt vmcnt(4)\n\ts_barrier" ::: "memory");
    if (s + 2 < ns) stage(s + 2, sb);
    G64_COMPUTE;
    rb = (rb == smem + 2 * 16384) ? smem : rb + 16384;
    sb = (sb == smem + 2 * 16384) ? smem : sb + 16384;
  }
  asm volatile("s_waitcnt vmcnt(0)\n\ts_barrier" ::: "memory");
  G64_COMPUTE;

  const int j = n0 + w * 16 + cl;
  const float bj = bias[j];
#pragma unroll
  for (int mi = 0; mi < 4; ++mi)
#pragma unroll
    for (int r = 0; r < 4; ++r) {
      const int row = m0 + mi * 16 + q * 4 + r;
      float v = acc[mi][r] + bj;
      if (mode == 0) {
        v = fmaxf(v, 0.f);
        const int b = row >> 1, l = row & 1;   // x rows are (b, l) pairs
        if (l == 0) { o0f[(long)b * HD + j] = v; o0b[(long)b * HD + j] = __float2bfloat16(v); }
        else        { o1f[(long)b * HD + j] = v; o1b[(long)b * HD + j] = __float2bfloat16(v); }
      } else {
        preds[((long)row * TT + t) * OD + j] = v;
        xbuf[(long)row * OD + j] = __float2bfloat16(v);
      }
    }
}

// ---- naive fallbacks (only if workspace too small for bf16 weights) ----
__global__ __launch_bounds__(256) void gru_cell_naive(
    const bf16* __restrict__ Ax, int Kx, const bf16* __restrict__ Ahb,
    const float* __restrict__ hprevf,
    const float* __restrict__ Wih, const float* __restrict__ Whh,
    const float* __restrict__ bih, const float* __restrict__ bhh,
    float* __restrict__ houtf, bf16* __restrict__ houtb) {
  const int idx = blockIdx.x * 256 + threadIdx.x;
  if (idx >= BB * HD) return;
  const int b = idx / HD, j = idx % HD;
  float gr = bih[j] + bhh[j], gz = bih[j + HD] + bhh[j + HD];
  float gnx = bih[j + 2 * HD], gnh = bhh[j + 2 * HD];
  for (int k = 0; k < Kx; ++k) {
    const float xv = __bfloat162float(Ax[(long)b * Kx + k]);
    gr += xv * Wih[(long)j * Kx + k];
    gz += xv * Wih[((long)j + HD) * Kx + k];
    gnx += xv * Wih[((long)j + 2 * HD) * Kx + k];
  }
  for (int k = 0; k < HD; ++k) {
    const float hv = __bfloat162float(Ahb[(long)b * HD + k]);
    gr += hv * Whh[(long)j * HD + k];
    gz += hv * Whh[((long)j + HD) * HD + k];
    gnh += hv * Whh[((long)j + 2 * HD) * HD + k];
  }
  const float rr = 1.f / (1.f + __expf(-gr));
  const float zz = 1.f / (1.f + __expf(-gz));
  const float nn = tanhf(gnx + rr * gnh);
  const float hp = hprevf[(long)b * HD + j];
  const float hn = (1.f - zz) * nn + zz * hp;
  houtf[(long)b * HD + j] = hn;
  houtb[(long)b * HD + j] = __float2bfloat16(hn);
}

__global__ __launch_bounds__(256) void naive_gemm(
    const void* __restrict__ A, int abf, const float* __restrict__ W,
    const float* __restrict__ bias, int N, int K, int mode, int t,
    float* __restrict__ o0f, bf16* __restrict__ o0b,
    float* __restrict__ o1f, bf16* __restrict__ o1b,
    float* __restrict__ preds, bf16* __restrict__ xbuf) {
  const long idx = (long)blockIdx.x * 256 + threadIdx.x;
  const int row = idx / N, j = idx % N;
  float v = bias[j];
  for (int k = 0; k < K; ++k) {
    const float av = abf ? __bfloat162float(((const bf16*)A)[(long)row * K + k])
                         : ((const float*)A)[(long)row * K + k];
    v += av * W[(long)j * K + k];
  }
  if (mode == 0) {
    v = fmaxf(v, 0.f);
    const int b = row >> 1, l = row & 1;
    if (l == 0) { o0f[(long)b * HD + j] = v; o0b[(long)b * HD + j] = __float2bfloat16(v); }
    else        { o1f[(long)b * HD + j] = v; o1b[(long)b * HD + j] = __float2bfloat16(v); }
  } else {
    preds[((long)row * TT + t) * OD + j] = v;
    xbuf[(long)row * OD + j] = __float2bfloat16(v);
  }
}

extern "C" void kernel_launch(void* const* d_in, const int* in_sizes, int n_in,
                              void* d_out, int out_size, void* d_ws, size_t ws_size,
                              hipStream_t stream) {
  const float* x    = (const float*)d_in[0];
  const float* embW = (const float*)d_in[1];
  const float* embb = (const float*)d_in[2];
  const float* Wih0 = (const float*)d_in[3];
  const float* Whh0 = (const float*)d_in[4];
  const float* bih0 = (const float*)d_in[5];
  const float* bhh0 = (const float*)d_in[6];
  const float* Wih1 = (const float*)d_in[7];
  const float* Whh1 = (const float*)d_in[8];
  const float* bih1 = (const float*)d_in[9];
  const float* bhh1 = (const float*)d_in[10];
  const float* outW = (const float*)d_in[11];
  const float* outb = (const float*)d_in[12];
  float* preds = (float*)d_out;

  char* p = (char*)d_ws;
  const size_t HF = (size_t)BB * HD * 4;
  const size_t HB = (size_t)BB * HD * 2;
  float* h0f[2] = {(float*)p, (float*)(p + HF)}; p += 2 * HF;
  float* h1f[2] = {(float*)p, (float*)(p + HF)}; p += 2 * HF;
  bf16* h0b[2] = {(bf16*)p, (bf16*)(p + HB)}; p += 2 * HB;
  bf16* h1b[2] = {(bf16*)p, (bf16*)(p + HB)}; p += 2 * HB;
  bf16* xbuf = (bf16*)p; p += (size_t)BB * OD * 2;

  const int nE = 2048 * 1024, nI0 = 6144 * 512, nH = 6144 * 2048,
            nO = 512 * 2048, nX = 1024 * 1024;
  const size_t conv_bytes = 2ul * (nE + nI0 + 3ul * nH + nO + nX);
  const bool big = ws_size >= (size_t)(p - (char*)d_ws) + conv_bytes;

  hipMemsetAsync(xbuf, 0, (size_t)BB * OD * 2, stream);  // zero input, steps 0-1

  if (big) {
    bf16* embWc = (bf16*)p; p += 2ul * nE;
    bf16* Wih0c = (bf16*)p; p += 2ul * nI0;
    bf16* Whh0c = (bf16*)p; p += 2ul * nH;
    bf16* Wih1c = (bf16*)p; p += 2ul * nH;
    bf16* Whh1c = (bf16*)p; p += 2ul * nH;
    bf16* outWc = (bf16*)p; p += 2ul * nO;
    bf16* xbf   = (bf16*)p; p += 2ul * nX;
    auto cv = [&](const float* s, bf16* d, int n) {
      cvt_kernel<<<(n / 4 + 255) / 256, 256, 0, stream>>>(s, d, n / 4);
    };
    cv(embW, embWc, nE); cv(Wih0, Wih0c, nI0); cv(Whh0, Whh0c, nH);
    cv(Wih1, Wih1c, nH); cv(Whh1, Whh1c, nH); cv(outW, outWc, nO);
    cv(x, xbf, nX);

    // embedding: xbf [1024,1024] -> h0/h1; 16 m-tiles x 32 n-tiles
    gemm64_kernel<<<512, 256, 0, stream>>>(
        xbf, embWc, embb, 1024, 0, 0, 2,
        h0f[0], h0b[0], h1f[0], h1b[0], nullptr, nullptr);

    for (int s = 0; s < 33; ++s) {
      const int cur = s & 1, nxt = cur ^ 1;
      gru_cell_kernel<<<256, 256, 0, stream>>>(
          xbuf, OD, h0b[cur], h0f[cur], Wih0c, Whh0c, bih0, bhh0,
          h0f[nxt], h0b[nxt]);
      gru_cell_kernel<<<256, 256, 0, stream>>>(
          h0b[nxt], HD, h1b[cur], h1f[cur], Wih1c, Whh1c, bih1, bhh1,
          h1f[nxt], h1b[nxt]);
      if (s >= 1)
        gemm64_kernel<<<64, 256, 0, stream>>>(
            h1b[nxt], outWc, outb, HD, 1, s - 1, 0,
            nullptr, nullptr, nullptr, nullptr, preds, xbuf);
    }
  } else {
    naive_gemm<<<(1024 * 2048) / 256, 256, 0, stream>>>(
        x, 0, embW, embb, 2048, 1024, 0, 0,
        h0f[0], h0b[0], h1f[0], h1b[0], nullptr, nullptr);
    for (int s = 0; s < 33; ++s) {
      const int cur = s & 1, nxt = cur ^ 1;
      gru_cell_naive<<<(BB * HD + 255) / 256, 256, 0, stream>>>(
          xbuf, OD, h0b[cur], h0f[cur], Wih0, Whh0, bih0, bhh0,
          h0f[nxt], h0b[nxt]);
      gru_cell_naive<<<(BB * HD + 255) / 256, 256, 0, stream>>>(
          h0b[nxt], HD, h1b[cur], h1f[cur], Wih1, Whh1, bih1, bhh1,
          h1f[nxt], h1b[nxt]);
      if (s >= 1)
        naive_gemm<<<(512 * 512) / 256, 256, 0, stream>>>(
            h1b[nxt], 1, outW, outb, 512, 2048, 1, s - 1,
            nullptr, nullptr, nullptr, nullptr, preds, xbuf);
    }
  }
}

// Round 7
// 2310.265 us; speedup vs baseline: 1.1815x; 1.1815x over previous
//
#include <hip/hip_runtime.h>
#include <hip/hip_bf16.h>

using bf16 = __hip_bfloat16;
typedef __attribute__((ext_vector_type(8))) short bf16x8;
typedef __attribute__((ext_vector_type(4))) float f32x4;

static constexpr int HD = 2048;   // hidden
static constexpr int BB = 512;    // batch
static constexpr int OD = 512;    // output dim
static constexpr int TT = 32;     // time steps

#define MFMA(a, b, c) __builtin_amdgcn_mfma_f32_16x16x32_bf16((a), (b), (c), 0, 0, 0)

__device__ __forceinline__ void gld16(const void* g, void* l) {
  __builtin_amdgcn_global_load_lds((const __attribute__((address_space(1))) void*)g,
                                   (__attribute__((address_space(3))) void*)l, 16, 0, 0);
}

// one-time fp32 -> bf16 conversion
__global__ __launch_bounds__(256) void cvt_kernel(const float* __restrict__ s,
                                                  bf16* __restrict__ d, int n4) {
  const int i = blockIdx.x * 256 + threadIdx.x;
  if (i < n4) {
    const float4 v = ((const float4*)s)[i];
    union { unsigned long long u; bf16 e[4]; } o;
    o.e[0] = __float2bfloat16(v.x); o.e[1] = __float2bfloat16(v.y);
    o.e[2] = __float2bfloat16(v.z); o.e[3] = __float2bfloat16(v.w);
    *(unsigned long long*)(d + 4l * i) = o.u;
  }
}

// Fused GRU cell, round-6 structure with the vmcnt race FIXED.
// r6 post-mortem: with 8 waves, A-waves issue 4 gld16/slice and W-waves 3,
// so r6's vmcnt(8)/vmcnt(6) were VACUOUS (outstanding == N at the wait) ->
// no wave verified slice s landed -> absmax 0.0059 fail. Strict T4 counts:
// wait until only slice s+1 remains in flight -> A: vmcnt(4), W: vmcnt(3).
// Slice s was issued 2 full steps (~2400cyc) before its wait >> ~900cyc HBM
// latency, so the strict wait is normally already satisfied (no perf cost).
// Structure: 512-thread block (8 waves), tile 128m x 32n x 3 gates, grid 256
// = 1 block/CU = 2 waves/SIMD (r4 occupancy) with 28KB/CU/step staged (r5
// bytes/MAC). Wave = 32m x 16n x 3g, 12 MFMA + 10 ds_read_b128 per BK=64
// step. 3-buffer depth-2; XOR swizzle (conflicts 0, r1-r5 verified).
// LDS 3 x 28KB ([A 16KB | W 12KB]). Waves 0-3 stage A, waves 4-7 stage W.
#define CELL_COMPUTE(NACC)                                                     \
  {                                                                            \
    const char* aB = rb + (wm * 32 + cl) * 128;                                \
    const char* wB = rb + 16384 + (wn * 16 + cl) * 128;                        \
    bf16x8 a00 = *(const bf16x8*)(aB + sc0);                                   \
    bf16x8 a01 = *(const bf16x8*)(aB + sc1);                                   \
    bf16x8 a10 = *(const bf16x8*)(aB + 2048 + sc0);                            \
    bf16x8 a11 = *(const bf16x8*)(aB + 2048 + sc1);                            \
    bf16x8 w00 = *(const bf16x8*)(wB + sc0);                                   \
    bf16x8 w01 = *(const bf16x8*)(wB + sc1);                                   \
    bf16x8 w10 = *(const bf16x8*)(wB + 4096 + sc0);                            \
    bf16x8 w11 = *(const bf16x8*)(wB + 4096 + sc1);                            \
    bf16x8 w20 = *(const bf16x8*)(wB + 8192 + sc0);                            \
    bf16x8 w21 = *(const bf16x8*)(wB + 8192 + sc1);                            \
    acc[0][0] = MFMA(a00, w00, acc[0][0]);                                     \
    acc[0][1] = MFMA(a10, w00, acc[0][1]);                                     \
    acc[1][0] = MFMA(a00, w10, acc[1][0]);                                     \
    acc[1][1] = MFMA(a10, w10, acc[1][1]);                                     \
    acc[NACC][0] = MFMA(a00, w20, acc[NACC][0]);                               \
    acc[NACC][1] = MFMA(a10, w20, acc[NACC][1]);                               \
    acc[0][0] = MFMA(a01, w01, acc[0][0]);                                     \
    acc[0][1] = MFMA(a11, w01, acc[0][1]);                                     \
    acc[1][0] = MFMA(a01, w11, acc[1][0]);                                     \
    acc[1][1] = MFMA(a11, w11, acc[1][1]);                                     \
    acc[NACC][0] = MFMA(a01, w21, acc[NACC][0]);                               \
    acc[NACC][1] = MFMA(a11, w21, acc[NACC][1]);                               \
  }

#define CELL_ROT(P) P = (P == smem + 2 * 28672) ? smem : P + 28672;

#define CELL_STEP(NACC, STAGE_CALL)                                            \
  {                                                                            \
    if (w < 4) asm volatile("s_waitcnt vmcnt(4)\n\ts_barrier" ::: "memory");   \
    else       asm volatile("s_waitcnt vmcnt(3)\n\ts_barrier" ::: "memory");   \
    STAGE_CALL;                                                                \
    CELL_COMPUTE(NACC);                                                        \
    CELL_ROT(rb); CELL_ROT(sb);                                                \
  }

#define CELL_STEP_LAST(NACC)                                                   \
  {                                                                            \
    asm volatile("s_waitcnt vmcnt(0)\n\ts_barrier" ::: "memory");              \
    CELL_COMPUTE(NACC);                                                        \
  }

__global__ __launch_bounds__(512) void gru_cell_kernel(
    const bf16* __restrict__ Ax, int Kx,        // [B, Kx] bf16 layer input
    const bf16* __restrict__ Ahb,               // [B, H] bf16 h shadow
    const float* __restrict__ hprevf,           // [B, H] fp32 h master
    const bf16* __restrict__ Wih,               // [3H, Kx] bf16
    const bf16* __restrict__ Whh,               // [3H, H] bf16
    const float* __restrict__ bih, const float* __restrict__ bhh,
    float* __restrict__ houtf, bf16* __restrict__ houtb) {
  __shared__ __align__(1024) char smem[3 * 28672];  // [A 16KB | W 12KB] x 3
  const int tid = threadIdx.x;
  const int lane = tid & 63;
  const int w = __builtin_amdgcn_readfirstlane(tid >> 6);  // 0..7
  const int wm = w >> 1, wn = w & 1;              // wave = 32m x 16n x 3g
  const int bid = blockIdx.x;
  const int rest = bid >> 3;
  const int m0 = (rest >> 3) * 128;               // 4 m-groups
  const int n0 = ((bid & 7) * 8 + (rest & 7)) * 32;  // same-n -> same XCD
  const int lr8 = lane >> 3;                       // stage: row within 8
  const int gsw = ((lane & 7) ^ lr8) << 3;         // stage: swizzled k-elem off
  const int cl = lane & 15, q = lane >> 4;
  const int sc0 = ((q ^ (cl & 7)) << 4);           // read: swizzled col, h=0
  const int sc1 = sc0 ^ 64;                        // h=1
  const int nsa = Kx >> 6, nsb = HD >> 6;

  // acc: 0=r, 1=z (both phases), 2=gx_n (A), 3=gh_n (B); [gate][m-frag]
  f32x4 acc[4][2];
#pragma unroll
  for (int a = 0; a < 4; ++a)
#pragma unroll
    for (int i = 0; i < 2; ++i) acc[a][i] = (f32x4){0.f, 0.f, 0.f, 0.f};

  // stage K-slice s (64 wide) into buffer at base. Each gld16: 8 rows x 128B
  // = 1KB. Waves 0-3: A (4 issues each, 16KB); waves 4-7: W (3 each, 12KB).
  auto stage = [&](const bf16* Ap, const bf16* Wp, int K, int s, char* base) {
    const int k0 = (s << 6) + gsw;
    if (w < 4) {
#pragma unroll
      for (int it = 0; it < 4; ++it) {
        const int r0 = (w * 4 + it) * 8;
        gld16(Ap + (long)(m0 + r0 + lr8) * K + k0, base + r0 * 128);
      }
    } else {
#pragma unroll
      for (int it = 0; it < 3; ++it) {
        const int jj = (w - 4) * 3 + it;           // 0..11: gate jj>>2, col (jj&3)*8
        gld16(Wp + ((long)(jj >> 2) * HD + n0 + (jj & 3) * 8 + lr8) * K + k0,
              base + 16384 + jj * 1024);
      }
    }
  };

  stage(Ax, Wih, Kx, 0, smem);
  stage(Ax, Wih, Kx, 1, smem + 28672);   // nsa >= 8 always, slice 1 is phase A
  char* rb = smem;
  char* sb = smem + 2 * 28672;

  for (int s = 0; s < nsa; ++s)                  // phase A: x @ Wih^T
    CELL_STEP(2, if (s + 2 < nsa) stage(Ax, Wih, Kx, s + 2, sb);
                 else stage(Ahb, Whh, HD, s + 2 - nsa, sb));
  for (int s = 0; s < nsb - 1; ++s)              // phase B: h @ Whh^T
    CELL_STEP(3, if (s + 2 < nsb) stage(Ahb, Whh, HD, s + 2, sb));
  CELL_STEP_LAST(3);

  // C/D layout: col=lane&15, row=(lane>>4)*4+reg (m89-verified)
  const int j = n0 + wn * 16 + cl;
  const float bihr = bih[j], bihz = bih[j + HD], bihn = bih[j + 2 * HD];
  const float bhhr = bhh[j], bhhz = bhh[j + HD], bhhn = bhh[j + 2 * HD];
#pragma unroll
  for (int mi = 0; mi < 2; ++mi)
#pragma unroll
    for (int r = 0; r < 4; ++r) {
      const int b = m0 + wm * 32 + mi * 16 + q * 4 + r;
      const float gr = acc[0][mi][r] + bihr + bhhr;
      const float gz = acc[1][mi][r] + bihz + bhhz;
      const float gnx = acc[2][mi][r] + bihn;
      const float gnh = acc[3][mi][r] + bhhn;
      const float rr = 1.f / (1.f + __expf(-gr));
      const float zz = 1.f / (1.f + __expf(-gz));
      const float nn = tanhf(gnx + rr * gnh);
      const float hp = hprevf[(long)b * HD + j];
      const float hn = (1.f - zz) * nn + zz * hp;
      houtf[(long)b * HD + j] = hn;
      houtb[(long)b * HD + j] = __float2bfloat16(hn);
    }
}

// C = A @ W^T + bias, tile 64m x 64n, 4 waves (wave = 64m x 16n), BK=64,
// 3-buffer depth-2 counted-vmcnt (strict: 4 issues/wave/slice -> vmcnt(4))
// + swizzle. Used for the embedding only.
#define G64_COMPUTE                                                            \
  {                                                                            \
    const char* aB = rb + cl * 128;                                            \
    const char* wB = rb + 8192 + (w * 16 + cl) * 128;                          \
    bf16x8 a00 = *(const bf16x8*)(aB + sc0);                                   \
    bf16x8 a01 = *(const bf16x8*)(aB + sc1);                                   \
    bf16x8 a10 = *(const bf16x8*)(aB + 2048 + sc0);                            \
    bf16x8 a11 = *(const bf16x8*)(aB + 2048 + sc1);                            \
    bf16x8 a20 = *(const bf16x8*)(aB + 4096 + sc0);                            \
    bf16x8 a21 = *(const bf16x8*)(aB + 4096 + sc1);                            \
    bf16x8 a30 = *(const bf16x8*)(aB + 6144 + sc0);                            \
    bf16x8 a31 = *(const bf16x8*)(aB + 6144 + sc1);                            \
    bf16x8 w0 = *(const bf16x8*)(wB + sc0);                                    \
    bf16x8 w1 = *(const bf16x8*)(wB + sc1);                                    \
    acc[0] = MFMA(a00, w0, acc[0]);                                            \
    acc[1] = MFMA(a10, w0, acc[1]);                                            \
    acc[2] = MFMA(a20, w0, acc[2]);                                            \
    acc[3] = MFMA(a30, w0, acc[3]);                                            \
    acc[0] = MFMA(a01, w1, acc[0]);                                            \
    acc[1] = MFMA(a11, w1, acc[1]);                                            \
    acc[2] = MFMA(a21, w1, acc[2]);                                            \
    acc[3] = MFMA(a31, w1, acc[3]);                                            \
  }

__global__ __launch_bounds__(256) void gemm64_kernel(
    const bf16* __restrict__ A, const bf16* __restrict__ W,
    const float* __restrict__ bias, int K, int mode, int t, int nbits,
    float* __restrict__ o0f, bf16* __restrict__ o0b,
    float* __restrict__ o1f, bf16* __restrict__ o1b,
    float* __restrict__ preds, bf16* __restrict__ xbuf) {
  __shared__ __align__(1024) char smem[3 * 16384];  // [A 8KB | W 8KB] x 3
  const int tid = threadIdx.x;
  const int lane = tid & 63;
  const int w = __builtin_amdgcn_readfirstlane(tid >> 6);
  const int bid = blockIdx.x;
  const int rest = bid >> 3;
  const int m0 = (rest >> nbits) * 64;
  const int n0 = (((bid & 7) << nbits) + (rest & ((1 << nbits) - 1))) * 64;
  const int lr8 = lane >> 3;
  const int gsw = ((lane & 7) ^ lr8) << 3;
  const int cl = lane & 15, q = lane >> 4;
  const int sc0 = ((q ^ (cl & 7)) << 4);
  const int sc1 = sc0 ^ 64;
  const int ns = K >> 6;

  f32x4 acc[4];
#pragma unroll
  for (int i = 0; i < 4; ++i) acc[i] = (f32x4){0.f, 0.f, 0.f, 0.f};

  auto stage = [&](int s, char* base) {
    const int k0 = (s << 6) + gsw;
    if (w < 2) {
#pragma unroll
      for (int it = 0; it < 4; ++it) {
        const int r0 = (w * 4 + it) * 8;
        gld16(A + (long)(m0 + r0 + lr8) * K + k0, base + r0 * 128);
      }
    } else {
#pragma unroll
      for (int it = 0; it < 4; ++it) {
        const int jj = (w - 2) * 4 + it;           // 0..7
        gld16(W + (long)(n0 + jj * 8 + lr8) * K + k0, base + 8192 + jj * 1024);
      }
    }
  };

  stage(0, smem);
  stage(1, smem + 16384);
  char* rb = smem;
  char* sb = smem + 2 * 16384;

  for (int s = 0; s < ns - 1; ++s) {
    asm volatile("s_waitcnt vmcnt(4)\n\ts_barrier" ::: "memory");
    if (s + 2 < ns) stage(s + 2, sb);
    G64_COMPUTE;
    rb = (rb == smem + 2 * 16384) ? smem : rb + 16384;
    sb = (sb == smem + 2 * 16384) ? smem : sb + 16384;
  }
  asm volatile("s_waitcnt vmcnt(0)\n\ts_barrier" ::: "memory");
  G64_COMPUTE;

  const int j = n0 + w * 16 + cl;
  const float bj = bias[j];
#pragma unroll
  for (int mi = 0; mi < 4; ++mi)
#pragma unroll
    for (int r = 0; r < 4; ++r) {
      const int row = m0 + mi * 16 + q * 4 + r;
      float v = acc[mi][r] + bj;
      if (mode == 0) {
        v = fmaxf(v, 0.f);
        const int b = row >> 1, l = row & 1;   // x rows are (b, l) pairs
        if (l == 0) { o0f[(long)b * HD + j] = v; o0b[(long)b * HD + j] = __float2bfloat16(v); }
        else        { o1f[(long)b * HD + j] = v; o1b[(long)b * HD + j] = __float2bfloat16(v); }
      } else {
        preds[((long)row * TT + t) * OD + j] = v;
        xbuf[(long)row * OD + j] = __float2bfloat16(v);
      }
    }
}

// Projection stage 1: partial C = A[:, kc*512:(kc+1)*512] @ W^T chunk.
// 64 tiles (64m x 64n) x 4 K-chunks = 256 blocks -> full device (old proj
// used 64 blocks = 75% idle). Same schedule as gemm64. Partials -> part.
__global__ __launch_bounds__(256) void gemm64p_kernel(
    const bf16* __restrict__ A,      // [512, 2048] h1b
    const bf16* __restrict__ W,      // [512, 2048] outWc
    float* __restrict__ part) {      // [4][512][512]
  __shared__ __align__(1024) char smem[3 * 16384];
  const int tid = threadIdx.x;
  const int lane = tid & 63;
  const int w = __builtin_amdgcn_readfirstlane(tid >> 6);
  const int bid = blockIdx.x;
  const int tile = bid & 63, kc = bid >> 6;
  const int m0 = (tile >> 3) * 64, n0 = (tile & 7) * 64;
  const int koff = kc << 9;
  const int lr8 = lane >> 3;
  const int gsw = ((lane & 7) ^ lr8) << 3;
  const int cl = lane & 15, q = lane >> 4;
  const int sc0 = ((q ^ (cl & 7)) << 4);
  const int sc1 = sc0 ^ 64;

  f32x4 acc[4];
#pragma unroll
  for (int i = 0; i < 4; ++i) acc[i] = (f32x4){0.f, 0.f, 0.f, 0.f};

  auto stage = [&](int s, char* base) {
    const int k0 = koff + (s << 6) + gsw;
    if (w < 2) {
#pragma unroll
      for (int it = 0; it < 4; ++it) {
        const int r0 = (w * 4 + it) * 8;
        gld16(A + (long)(m0 + r0 + lr8) * HD + k0, base + r0 * 128);
      }
    } else {
#pragma unroll
      for (int it = 0; it < 4; ++it) {
        const int jj = (w - 2) * 4 + it;
        gld16(W + (long)(n0 + jj * 8 + lr8) * HD + k0, base + 8192 + jj * 1024);
      }
    }
  };

  stage(0, smem);
  stage(1, smem + 16384);
  char* rb = smem;
  char* sb = smem + 2 * 16384;

  for (int s = 0; s < 7; ++s) {                   // ns = 512/64 = 8
    asm volatile("s_waitcnt vmcnt(4)\n\ts_barrier" ::: "memory");
    if (s + 2 < 8) stage(s + 2, sb);
    G64_COMPUTE;
    rb = (rb == smem + 2 * 16384) ? smem : rb + 16384;
    sb = (sb == smem + 2 * 16384) ? smem : sb + 16384;
  }
  asm volatile("s_waitcnt vmcnt(0)\n\ts_barrier" ::: "memory");
  G64_COMPUTE;

  const int j = n0 + w * 16 + cl;
  float* dst = part + ((long)kc << 18);
#pragma unroll
  for (int mi = 0; mi < 4; ++mi)
#pragma unroll
    for (int r = 0; r < 4; ++r) {
      const int row = m0 + mi * 16 + q * 4 + r;
      dst[(long)row * OD + j] = acc[mi][r];
    }
}

// Projection stage 2: sum 4 partials + bias -> preds (f32) + xbuf (bf16).
__global__ __launch_bounds__(256) void proj_combine(
    const float* __restrict__ part, const float* __restrict__ bias, int t,
    float* __restrict__ preds, bf16* __restrict__ xbuf) {
  const int i = blockIdx.x * 256 + threadIdx.x;   // 65536 threads x float4
  const int row = i >> 7, j0 = (i & 127) << 2;
  const float4* P = (const float4*)part;
  const float4 p0 = P[i], p1 = P[65536 + i], p2 = P[131072 + i], p3 = P[196608 + i];
  const float4 b4 = ((const float4*)bias)[i & 127];
  float4 v;
  v.x = p0.x + p1.x + p2.x + p3.x + b4.x;
  v.y = p0.y + p1.y + p2.y + p3.y + b4.y;
  v.z = p0.z + p1.z + p2.z + p3.z + b4.z;
  v.w = p0.w + p1.w + p2.w + p3.w + b4.w;
  *(float4*)(preds + ((long)row * TT + t) * OD + j0) = v;
  union { unsigned long long u; bf16 e[4]; } o;
  o.e[0] = __float2bfloat16(v.x); o.e[1] = __float2bfloat16(v.y);
  o.e[2] = __float2bfloat16(v.z); o.e[3] = __float2bfloat16(v.w);
  *(unsigned long long*)(xbuf + (long)row * OD + j0) = o.u;
}

// ---- naive fallbacks (only if workspace too small for bf16 weights) ----
__global__ __launch_bounds__(256) void gru_cell_naive(
    const bf16* __restrict__ Ax, int Kx, const bf16* __restrict__ Ahb,
    const float* __restrict__ hprevf,
    const float* __restrict__ Wih, const float* __restrict__ Whh,
    const float* __restrict__ bih, const float* __restrict__ bhh,
    float* __restrict__ houtf, bf16* __restrict__ houtb) {
  const int idx = blockIdx.x * 256 + threadIdx.x;
  if (idx >= BB * HD) return;
  const int b = idx / HD, j = idx % HD;
  float gr = bih[j] + bhh[j], gz = bih[j + HD] + bhh[j + HD];
  float gnx = bih[j + 2 * HD], gnh = bhh[j + 2 * HD];
  for (int k = 0; k < Kx; ++k) {
    const float xv = __bfloat162float(Ax[(long)b * Kx + k]);
    gr += xv * Wih[(long)j * Kx + k];
    gz += xv * Wih[((long)j + HD) * Kx + k];
    gnx += xv * Wih[((long)j + 2 * HD) * Kx + k];
  }
  for (int k = 0; k < HD; ++k) {
    const float hv = __bfloat162float(Ahb[(long)b * HD + k]);
    gr += hv * Whh[(long)j * HD + k];
    gz += hv * Whh[((long)j + HD) * HD + k];
    gnh += hv * Whh[((long)j + 2 * HD) * HD + k];
  }
  const float rr = 1.f / (1.f + __expf(-gr));
  const float zz = 1.f / (1.f + __expf(-gz));
  const float nn = tanhf(gnx + rr * gnh);
  const float hp = hprevf[(long)b * HD + j];
  const float hn = (1.f - zz) * nn + zz * hp;
  houtf[(long)b * HD + j] = hn;
  houtb[(long)b * HD + j] = __float2bfloat16(hn);
}

__global__ __launch_bounds__(256) void naive_gemm(
    const void* __restrict__ A, int abf, const float* __restrict__ W,
    const float* __restrict__ bias, int N, int K, int mode, int t,
    float* __restrict__ o0f, bf16* __restrict__ o0b,
    float* __restrict__ o1f, bf16* __restrict__ o1b,
    float* __restrict__ preds, bf16* __restrict__ xbuf) {
  const long idx = (long)blockIdx.x * 256 + threadIdx.x;
  const int row = idx / N, j = idx % N;
  float v = bias[j];
  for (int k = 0; k < K; ++k) {
    const float av = abf ? __bfloat162float(((const bf16*)A)[(long)row * K + k])
                         : ((const float*)A)[(long)row * K + k];
    v += av * W[(long)j * K + k];
  }
  if (mode == 0) {
    v = fmaxf(v, 0.f);
    const int b = row >> 1, l = row & 1;
    if (l == 0) { o0f[(long)b * HD + j] = v; o0b[(long)b * HD + j] = __float2bfloat16(v); }
    else        { o1f[(long)b * HD + j] = v; o1b[(long)b * HD + j] = __float2bfloat16(v); }
  } else {
    preds[((long)row * TT + t) * OD + j] = v;
    xbuf[(long)row * OD + j] = __float2bfloat16(v);
  }
}

extern "C" void kernel_launch(void* const* d_in, const int* in_sizes, int n_in,
                              void* d_out, int out_size, void* d_ws, size_t ws_size,
                              hipStream_t stream) {
  const float* x    = (const float*)d_in[0];
  const float* embW = (const float*)d_in[1];
  const float* embb = (const float*)d_in[2];
  const float* Wih0 = (const float*)d_in[3];
  const float* Whh0 = (const float*)d_in[4];
  const float* bih0 = (const float*)d_in[5];
  const float* bhh0 = (const float*)d_in[6];
  const float* Wih1 = (const float*)d_in[7];
  const float* Whh1 = (const float*)d_in[8];
  const float* bih1 = (const float*)d_in[9];
  const float* bhh1 = (const float*)d_in[10];
  const float* outW = (const float*)d_in[11];
  const float* outb = (const float*)d_in[12];
  float* preds = (float*)d_out;

  char* p = (char*)d_ws;
  const size_t HF = (size_t)BB * HD * 4;
  const size_t HB = (size_t)BB * HD * 2;
  float* h0f[2] = {(float*)p, (float*)(p + HF)}; p += 2 * HF;
  float* h1f[2] = {(float*)p, (float*)(p + HF)}; p += 2 * HF;
  bf16* h0b[2] = {(bf16*)p, (bf16*)(p + HB)}; p += 2 * HB;
  bf16* h1b[2] = {(bf16*)p, (bf16*)(p + HB)}; p += 2 * HB;
  bf16* xbuf = (bf16*)p; p += (size_t)BB * OD * 2;
  float* projp = (float*)p; p += 4ul * BB * OD * 4;   // [4][512][512] partials

  const int nE = 2048 * 1024, nI0 = 6144 * 512, nH = 6144 * 2048,
            nO = 512 * 2048, nX = 1024 * 1024;
  const size_t conv_bytes = 2ul * (nE + nI0 + 3ul * nH + nO + nX);
  const bool big = ws_size >= (size_t)(p - (char*)d_ws) + conv_bytes;

  hipMemsetAsync(xbuf, 0, (size_t)BB * OD * 2, stream);  // zero input, steps 0-1

  if (big) {
    bf16* embWc = (bf16*)p; p += 2ul * nE;
    bf16* Wih0c = (bf16*)p; p += 2ul * nI0;
    bf16* Whh0c = (bf16*)p; p += 2ul * nH;
    bf16* Wih1c = (bf16*)p; p += 2ul * nH;
    bf16* Whh1c = (bf16*)p; p += 2ul * nH;
    bf16* outWc = (bf16*)p; p += 2ul * nO;
    bf16* xbf   = (bf16*)p; p += 2ul * nX;
    auto cv = [&](const float* s, bf16* d, int n) {
      cvt_kernel<<<(n / 4 + 255) / 256, 256, 0, stream>>>(s, d, n / 4);
    };
    cv(embW, embWc, nE); cv(Wih0, Wih0c, nI0); cv(Whh0, Whh0c, nH);
    cv(Wih1, Wih1c, nH); cv(Whh1, Whh1c, nH); cv(outW, outWc, nO);
    cv(x, xbf, nX);

    // embedding: xbf [1024,1024] -> h0/h1; 16 m-tiles x 32 n-tiles
    gemm64_kernel<<<512, 256, 0, stream>>>(
        xbf, embWc, embb, 1024, 0, 0, 2,
        h0f[0], h0b[0], h1f[0], h1b[0], nullptr, nullptr);

    for (int s = 0; s < 33; ++s) {
      const int cur = s & 1, nxt = cur ^ 1;
      gru_cell_kernel<<<256, 512, 0, stream>>>(
          xbuf, OD, h0b[cur], h0f[cur], Wih0c, Whh0c, bih0, bhh0,
          h0f[nxt], h0b[nxt]);
      gru_cell_kernel<<<256, 512, 0, stream>>>(
          h0b[nxt], HD, h1b[cur], h1f[cur], Wih1c, Whh1c, bih1, bhh1,
          h1f[nxt], h1b[nxt]);
      if (s >= 1) {
        gemm64p_kernel<<<256, 256, 0, stream>>>(h1b[nxt], outWc, projp);
        proj_combine<<<256, 256, 0, stream>>>(projp, outb, s - 1, preds, xbuf);
      }
    }
  } else {
    naive_gemm<<<(1024 * 2048) / 256, 256, 0, stream>>>(
        x, 0, embW, embb, 2048, 1024, 0, 0,
        h0f[0], h0b[0], h1f[0], h1b[0], nullptr, nullptr);
    for (int s = 0; s < 33; ++s) {
      const int cur = s & 1, nxt = cur ^ 1;
      gru_cell_naive<<<(BB * HD + 255) / 256, 256, 0, stream>>>(
          xbuf, OD, h0b[cur], h0f[cur], Wih0, Whh0, bih0, bhh0,
          h0f[nxt], h0b[nxt]);
      gru_cell_naive<<<(BB * HD + 255) / 256, 256, 0, stream>>>(
          h0b[nxt], HD, h1b[cur], h1f[cur], Wih1, Whh1, bih1, bhh1,
          h1f[nxt], h1b[nxt]);
      if (s >= 1)
        naive_gemm<<<(512 * 512) / 256, 256, 0, stream>>>(
            h1b[nxt], 1, outW, outb, 512, 2048, 1, s - 1,
            nullptr, nullptr, nullptr, nullptr, preds, xbuf);
    }
  }
}